// Round 6
// baseline (244.953 us; speedup 1.0000x reference)
//
#include <hip/hip_runtime.h>
#include <math.h>

#define N_NODES 50000
#define N_EDGES 800000
#define NBK 196          // dst buckets of 256 nodes: bucket = dst >> 8
#define BCAP 6144        // max edges per bucket handled in LDS (mean 4082, sigma 64)

typedef short short8 __attribute__((ext_vector_type(8)));
typedef float f32x4 __attribute__((ext_vector_type(4)));
typedef float f32x2 __attribute__((ext_vector_type(2)));

// ---------------- bf16 / fp8 helpers ----------------
__device__ inline unsigned short f2bf(float v) {
  unsigned u = __float_as_uint(v);
  u += 0x7FFFu + ((u >> 16) & 1u);  // round-to-nearest-even
  return (unsigned short)(u >> 16);
}
__device__ inline float bf2f(unsigned short b) {
  return __uint_as_float(((unsigned)b) << 16);
}
__device__ inline float bflo(unsigned u) { return __uint_as_float(u << 16); }
__device__ inline float bfhi(unsigned u) { return __uint_as_float(u & 0xFFFF0000u); }
// fp8 e4m3 (OCP on gfx950); decode selector must be an immediate -> template param.
__device__ inline unsigned char f2fp8(float v) {
  return (unsigned char)(__builtin_amdgcn_cvt_pk_fp8_f32(v, 0.f, 0, false) & 0xFF);
}
template <bool HI>
__device__ inline f32x2 fp8dec(unsigned u) {
  return __builtin_amdgcn_cvt_pk_f32_fp8(u, HI);
}

#define SCL 0.17677669529663687f   // 1/sqrt(32), folded into Wq/bq at prep
#define W1_B 256      // 512*128 / 256
#define W2_B 64       // 128*128 / 256

// ================= L1: bucket histogram only =================
__global__ void edge_hist(const int* __restrict__ ei, int* __restrict__ bhist, int E) {
  __shared__ int h[NBK];
  const int tid = threadIdx.x;
  for (int i = tid; i < NBK; i += 256) h[i] = 0;
  __syncthreads();
  int e = blockIdx.x * 4096 + tid;
#pragma unroll
  for (int p = 0; p < 16; ++p, e += 256)
    if (e < E) atomicAdd(&h[ei[E + e] >> 8], 1);
  __syncthreads();
  for (int i = tid; i < NBK; i += 256)
    if (h[i]) atomicAdd(&bhist[i], h[i]);
}

// ================= L2: bucket scatter (blocks [0,EB)) + weight prep (rest) =========
// Scatter computes the 196-int exclusive prefix of bhist LOCALLY (replaces the old
// bucket_scan kernel); bcur is zero-initialized, chunk base = bl[i] + atomicAdd(bcur[i]).
// Slot assignment identical to the r0/r1-verified two-phase scheme (write-combining
// friendly: each block owns contiguous chunks per bucket; WRITE == logical size).
__global__ void scatter_w(const int* __restrict__ ei, const int* __restrict__ bhist,
                          int* __restrict__ bcur, int* __restrict__ ebuck, int E, int EB,
                          const float* __restrict__ Wq1, const float* __restrict__ Wk1,
                          const float* __restrict__ Wv1, const float* __restrict__ Ws1,
                          const float* __restrict__ bq1, const float* __restrict__ bk1,
                          const float* __restrict__ bv1, const float* __restrict__ bs1,
                          const float* __restrict__ Wq2, const float* __restrict__ Wk2,
                          const float* __restrict__ Wv2, const float* __restrict__ Ws2,
                          const float* __restrict__ bq2, const float* __restrict__ bk2,
                          const float* __restrict__ bv2, const float* __restrict__ bs2,
                          unsigned short* __restrict__ Wt1, float* __restrict__ bcat1,
                          unsigned short* __restrict__ Wt2, float* __restrict__ bcat2) {
  const int b = blockIdx.x, tid = threadIdx.x;
  if (b < EB) {
    __shared__ int sc[256];
    __shared__ int bl[256];
    __shared__ int lh[256];
    const int t = tid;
    int v = (t < NBK) ? bhist[t] : 0;
    sc[t] = v;
    __syncthreads();
#pragma unroll
    for (int off = 1; off < 256; off <<= 1) {
      int u = (t >= off) ? sc[t - off] : 0;
      __syncthreads();
      sc[t] += u;
      __syncthreads();
    }
    bl[t] = sc[t] - v;    // exclusive prefix == old boff[t]
    lh[t] = 0;
    __syncthreads();
    const int e0 = b * 4096;
    int pks[16], bks[16];
#pragma unroll
    for (int p = 0; p < 16; ++p) {
      int e = e0 + p * 256 + tid;
      if (e < E) {
        int src = ei[e], dst = ei[E + e];
        pks[p] = (src << 8) | (dst & 255);
        bks[p] = dst >> 8;
        atomicAdd(&lh[bks[p]], 1);
      } else bks[p] = -1;
    }
    __syncthreads();
    for (int i = tid; i < NBK; i += 256)
      if (lh[i]) lh[i] = bl[i] + atomicAdd(&bcur[i], lh[i]);
    __syncthreads();
#pragma unroll
    for (int p = 0; p < 16; ++p) {
      if (bks[p] >= 0) {
        int slot = atomicAdd(&lh[bks[p]], 1);
        ebuck[slot] = pks[p];
      }
    }
    return;
  }
  const int b2 = b - EB;
  if (b2 < W1_B) {
    int i = b2 * 256 + tid;   // over 512*128
    int c = i >> 7, k = i & 127;
    int mi = c >> 7, lc = c & 127;
    const float* W = (mi == 0) ? Wq1 : (mi == 1) ? Wk1 : (mi == 2) ? Wv1 : Ws1;
    float scl = (mi == 0) ? SCL : 1.f;
    Wt1[i] = f2bf(W[(size_t)k * 128 + lc] * scl);
    if (i < 512) {
      int bm = i >> 7, blx = i & 127;
      const float* bb = (bm == 0) ? bq1 : (bm == 1) ? bk1 : (bm == 2) ? bv1 : bs1;
      bcat1[i] = bb[blx] * ((bm == 0) ? SCL : 1.f);
    }
  } else {
    int i = (b2 - W1_B) * 256 + tid;  // over 128*128
    int c = i >> 7, k = i & 127;
    int mi = c >> 5, lc = c & 31;
    const float* W = (mi == 0) ? Wq2 : (mi == 1) ? Wk2 : (mi == 2) ? Wv2 : Ws2;
    float scl = (mi == 0) ? SCL : 1.f;
    Wt2[i] = f2bf(W[(size_t)k * 32 + lc] * scl);
    if (i < 128) {
      int bm = i >> 5, blx = i & 31;
      const float* bb = (bm == 0) ? bq2 : (bm == 1) ? bk2 : (bm == 2) ? bv2 : bs2;
      bcat2[i] = bb[blx] * ((bm == 0) ? SCL : 1.f);
    }
  }
}

// ================= L3: bucket_csr (blocks [0,NBK)) + conv1 GEMM (blocks [NBK,..)) ====
// Pairing rationale (r6): csr depends on the scatter, gemm1 only on weights -- so csr's
// ~12 us (196 blocks, machine mostly idle standalone) hides under gemm1's ~30 us launch.
// csr computes lo/hi from a local bhist prefix scan (bucket_scan kernel deleted).
// GEMM: 64 rows x 512 cols in TWO 256-col passes (acc[4][4]) keeping natural VGPR well
// below the 168 hint (r2 lesson: binding caps -> catastrophic spill roulette).
// r4 lesson: do NOT barrier-fuse attention with GEMMs (max-over-waves imbalance).
// KV fp8 row (256 B/node): byte 4t+{0,1} = K[2t,2t+1], byte 4t+{2,3} = V[2t,2t+1].
__global__ __launch_bounds__(256, 3) void csr_gemm1(
    const int* __restrict__ ebuck, const int* __restrict__ bhist,
    int* __restrict__ rowptr, int* __restrict__ esrc, int N,
    const float* __restrict__ X, const unsigned short* __restrict__ Wt,
    const float* __restrict__ bcat, unsigned short* __restrict__ Q1b,
    unsigned short* __restrict__ SK1, unsigned char* __restrict__ KV8, int M) {
  __shared__ __align__(16) unsigned char L[3 * 64 * 272];  // 52.2 KB flat
  const int tid = threadIdx.x;

  if ((int)blockIdx.x < NBK) {
    // ---------- bucket_csr path (LDS: 4x256 ints + BCAP ints = 28.7 KB of L) ----------
    int* s_scan = (int*)L;                 // 256 ints
    int* hv     = (int*)(L + 1024);        // 256 ints
    int* hist   = (int*)(L + 2048);        // 256 ints
    int* cur    = (int*)(L + 3072);        // 256 ints
    int* sorted = (int*)(L + 4096);        // BCAP ints
    const int b = blockIdx.x, t = tid;
    int v = (t < NBK) ? bhist[t] : 0;
    hv[t] = v;
    s_scan[t] = v;
    __syncthreads();
#pragma unroll
    for (int off = 1; off < 256; off <<= 1) {
      int u = (t >= off) ? s_scan[t - off] : 0;
      __syncthreads();
      s_scan[t] += u;
      __syncthreads();
    }
    const int lo = s_scan[b] - hv[b], hi = s_scan[b];
    const int cnt = hi - lo;
    hist[t] = 0;
    __syncthreads();
    for (int i = t; i < cnt; i += 256) atomicAdd(&hist[ebuck[lo + i] & 255], 1);
    __syncthreads();
    int v2 = hist[t];
    sorted[t] = v2;
    __syncthreads();
#pragma unroll
    for (int off = 1; off < 256; off <<= 1) {
      int u = (t >= off) ? sorted[t - off] : 0;
      __syncthreads();
      sorted[t] += u;
      __syncthreads();
    }
    int excl = sorted[t] - v2;
    cur[t] = excl;
    int node = b * 256 + t;
    if (node <= N) rowptr[node] = lo + excl;
    __syncthreads();
    for (int i = t; i < cnt; i += 256) {
      int pk = ebuck[lo + i];
      int slot = atomicAdd(&cur[pk & 255], 1);
      if (slot < BCAP) sorted[slot] = pk;
      else esrc[lo + slot] = pk & 0xFFFFFF00;
    }
    __syncthreads();
    int lim = cnt < BCAP ? cnt : BCAP;
    for (int i = t; i < lim; i += 256) esrc[lo + i] = sorted[i] & 0xFFFFFF00;
    return;
  }

  // ---------- GEMM path (two passes, low register pressure) ----------
  unsigned short* As = (unsigned short*)L;                // stride 136 shorts
  unsigned short* L1 = (unsigned short*)(L + 17408);
  unsigned char*  L2 = L + 34816;
  const int bm = (blockIdx.x - NBK) * 64;
  const int wave = tid >> 6, lane = tid & 63;
  const int lr = lane & 15, q = lane >> 4;

#pragma unroll
  for (int p = 0; p < 8; ++p) {
    int f = tid + p * 256;          // 0..2047 float4s
    int row = f >> 5, c4 = f & 31;
    int gm = bm + row; if (gm >= M) gm = 0;
    float4 v = *(const float4*)(X + (size_t)gm * 128 + c4 * 4);
    ushort4 o;
    o.x = f2bf(v.x); o.y = f2bf(v.y); o.z = f2bf(v.z); o.w = f2bf(v.w);
    *(ushort4*)&As[row * 136 + c4 * 4] = o;
  }
  __syncthreads();

#pragma unroll
  for (int pass = 0; pass < 2; ++pass) {
    const int colbase = pass * 256 + wave * 64;
    f32x4 acc[4][4];
#pragma unroll
    for (int i = 0; i < 4; ++i)
#pragma unroll
      for (int j = 0; j < 4; ++j) acc[i][j] = (f32x4){0.f, 0.f, 0.f, 0.f};

#pragma unroll
    for (int ks = 0; ks < 4; ++ks) {
      short8 af[4];
#pragma unroll
      for (int i = 0; i < 4; ++i)
        af[i] = *(short8*)&As[(i * 16 + lr) * 136 + ks * 32 + q * 8];
#pragma unroll
      for (int j = 0; j < 4; ++j) {
        short8 bf = *(const short8*)(Wt + (size_t)(colbase + j * 16 + lr) * 128 + ks * 32 + q * 8);
#pragma unroll
        for (int i = 0; i < 4; ++i)
          acc[i][j] = __builtin_amdgcn_mfma_f32_16x16x32_bf16(af[i], bf, acc[i][j], 0, 0, 0);
      }
    }

    float bj[4];
#pragma unroll
    for (int j = 0; j < 4; ++j) bj[j] = bcat[colbase + j * 16 + lr];

    if (pass == 0) {
      if (wave < 2) {          // Q cols 0..127 -> L1 bf16
#pragma unroll
        for (int i = 0; i < 4; ++i)
#pragma unroll
          for (int r = 0; r < 4; ++r) {
            int row = i * 16 + q * 4 + r;
#pragma unroll
            for (int j = 0; j < 4; ++j)
              L1[row * 136 + wave * 64 + j * 16 + lr] = f2bf(acc[i][j][r] + bj[j]);
          }
      } else {                 // K dims 0..127 -> L2 fp8 (voff 0)
#pragma unroll
        for (int i = 0; i < 4; ++i)
#pragma unroll
          for (int r = 0; r < 4; ++r) {
            int row = i * 16 + q * 4 + r;
#pragma unroll
            for (int j = 0; j < 4; ++j) {
              int d = (wave - 2) * 64 + j * 16 + lr;
              L2[row * 272 + 4 * (d >> 1) + (d & 1)] = f2fp8(acc[i][j][r] + bj[j]);
            }
          }
      }
    } else {
      __syncthreads();         // all As reads complete before SK overwrites L[0..]
      if (wave < 2) {          // V dims 0..127 -> L2 fp8 (voff 2)
#pragma unroll
        for (int i = 0; i < 4; ++i)
#pragma unroll
          for (int r = 0; r < 4; ++r) {
            int row = i * 16 + q * 4 + r;
#pragma unroll
            for (int j = 0; j < 4; ++j) {
              int d = wave * 64 + j * 16 + lr;
              L2[row * 272 + 4 * (d >> 1) + 2 + (d & 1)] = f2fp8(acc[i][j][r] + bj[j]);
            }
          }
      } else {                 // SK cols 0..127 -> As region bf16 (no longer needed)
#pragma unroll
        for (int i = 0; i < 4; ++i)
#pragma unroll
          for (int r = 0; r < 4; ++r) {
            int row = i * 16 + q * 4 + r;
#pragma unroll
            for (int j = 0; j < 4; ++j)
              As[row * 136 + (wave - 2) * 64 + j * 16 + lr] = f2bf(acc[i][j][r] + bj[j]);
          }
      }
    }
  }
  __syncthreads();

#pragma unroll
  for (int p = 0; p < 4; ++p) {
    int f = tid + p * 256;
    int row = f >> 4, u = f & 15;
    int gr = bm + row;
    if (gr < M) {
      *(uint4*)(Q1b + (size_t)gr * 128 + u * 8) = *(uint4*)&L1[row * 136 + u * 8];
      *(uint4*)(KV8 + (size_t)gr * 256 + u * 16) = *(uint4*)&L2[row * 272 + u * 16];
      *(uint4*)(SK1 + (size_t)gr * 128 + u * 8) = *(uint4*)&As[row * 136 + u * 8];
    }
  }
}

// ---- gemm2: LDS-staged A (bf16); 128 cols -> C2 rows (256 B): [Q bf16 | KV fp8 | pad | H bf16] ----
__global__ __launch_bounds__(256) void gemm2(
    const unsigned short* __restrict__ Ab, const unsigned short* __restrict__ Wt,
    const float* __restrict__ bcat, unsigned char* __restrict__ C2b, int M) {
  __shared__ __align__(16) unsigned short As[64 * 136];
  __shared__ __align__(16) unsigned char Lsb[64 * 272];
  const int bm = blockIdx.x * 64;
  const int tid = threadIdx.x, wave = tid >> 6, lane = tid & 63;
  const int lr = lane & 15, q = lane >> 4;

#pragma unroll
  for (int p = 0; p < 4; ++p) {
    int f = tid + p * 256;
    int row = f >> 4, chunk = f & 15;
    int gm = bm + row; if (gm >= M) gm = 0;
    uint4 v = *(const uint4*)(Ab + (size_t)gm * 128 + chunk * 8);
    *(uint4*)&As[row * 136 + chunk * 8] = v;
  }
  __syncthreads();

  f32x4 acc[4][2];
#pragma unroll
  for (int i = 0; i < 4; ++i)
#pragma unroll
    for (int j = 0; j < 2; ++j) acc[i][j] = (f32x4){0.f, 0.f, 0.f, 0.f};

#pragma unroll
  for (int ks = 0; ks < 4; ++ks) {
    short8 af[4];
#pragma unroll
    for (int i = 0; i < 4; ++i)
      af[i] = *(short8*)&As[(i * 16 + lr) * 136 + ks * 32 + q * 8];
#pragma unroll
    for (int j = 0; j < 2; ++j) {
      short8 bf = *(const short8*)(Wt + (size_t)(wave * 32 + j * 16 + lr) * 128 + ks * 32 + q * 8);
#pragma unroll
      for (int i = 0; i < 4; ++i)
        acc[i][j] = __builtin_amdgcn_mfma_f32_16x16x32_bf16(af[i], bf, acc[i][j], 0, 0, 0);
    }
  }

  float bj[2];
#pragma unroll
  for (int j = 0; j < 2; ++j) bj[j] = bcat[wave * 32 + j * 16 + lr];
#pragma unroll
  for (int i = 0; i < 4; ++i)
#pragma unroll
    for (int r = 0; r < 4; ++r) {
      int row = i * 16 + q * 4 + r;
#pragma unroll
      for (int j = 0; j < 2; ++j) {
        int c = wave * 32 + j * 16 + lr;
        float val = acc[i][j][r] + bj[j];
        if (c < 32) {
          *(unsigned short*)&Lsb[row * 272 + 2 * c] = f2bf(val);
        } else if (c < 64) {
          int d = c - 32;
          Lsb[row * 272 + 64 + 4 * (d >> 1) + (d & 1)] = f2fp8(val);
        } else if (c < 96) {
          int d = c - 64;
          Lsb[row * 272 + 64 + 4 * (d >> 1) + 2 + (d & 1)] = f2fp8(val);
        } else {
          *(unsigned short*)&Lsb[row * 272 + 192 + 2 * (c - 96)] = f2bf(val);
        }
      }
    }
  __syncthreads();
#pragma unroll
  for (int p = 0; p < 16; ++p) {
    int idx = tid + p * 256;
    int row = idx >> 6, u = idx & 63;
    int gr = bm + row;
    if (gr < M) *(unsigned*)(C2b + (size_t)gr * 256 + u * 4) = *(const unsigned*)&Lsb[row * 272 + u * 4];
  }
}

// ================= fused aggregation: plain-exp softmax, fp8 K/V =================
// conv1: 16 lanes per edge (4 groups), uint4 (16 B/lane) KV loads; 2 edges in flight.
__global__ void node_attn1(const int* __restrict__ rowptr, const int* __restrict__ esrc,
                           const unsigned short* __restrict__ Qb,
                           const unsigned char* __restrict__ KV8,
                           const unsigned short* __restrict__ SK, unsigned short* __restrict__ Hb,
                           int n) {
  int node = (blockIdx.x * blockDim.x + threadIdx.x) >> 6;
  int lane = threadIdx.x & 63;
  if (node >= n) return;
  const int g = lane >> 4, ll = lane & 15;   // 4 groups x 16 lanes
  const int r0 = rowptr[node], r1 = rowptr[node + 1];
  uint4 qq = *(const uint4*)(Qb + (size_t)node * 128 + ll * 8);
  const float q0 = bflo(qq.x), q1 = bfhi(qq.x), q2 = bflo(qq.y), q3 = bfhi(qq.y);
  const float q4 = bflo(qq.z), q5 = bfhi(qq.z), q6 = bflo(qq.w), q7 = bfhi(qq.w);
  float l = 0.f;
  float a0 = 0.f, a1 = 0.f, a2 = 0.f, a3 = 0.f, a4 = 0.f, a5 = 0.f, a6 = 0.f, a7 = 0.f;
  const unsigned char* kvb = KV8 + ll * 16;
  int j = r0;
  for (; j + 8 <= r1; j += 8) {      // 8 edges/wave-iter: 4 groups x 2 edges
    int e = j + g * 2;
    int sA = esrc[e], sB = esrc[e + 1];
    uint4 uA = *(const uint4*)(kvb + sA);
    uint4 uB = *(const uint4*)(kvb + sB);
    f32x2 kA0 = fp8dec<false>(uA.x), kA1 = fp8dec<false>(uA.y),
          kA2 = fp8dec<false>(uA.z), kA3 = fp8dec<false>(uA.w);
    f32x2 kB0 = fp8dec<false>(uB.x), kB1 = fp8dec<false>(uB.y),
          kB2 = fp8dec<false>(uB.z), kB3 = fp8dec<false>(uB.w);
    float dA = q0 * kA0.x + q1 * kA0.y + q2 * kA1.x + q3 * kA1.y
             + q4 * kA2.x + q5 * kA2.y + q6 * kA3.x + q7 * kA3.y;
    float dB = q0 * kB0.x + q1 * kB0.y + q2 * kB1.x + q3 * kB1.y
             + q4 * kB2.x + q5 * kB2.y + q6 * kB3.x + q7 * kB3.y;
#pragma unroll
    for (int msk = 1; msk <= 2; msk <<= 1) {   // reduce within 4-lane heads
      dA += __shfl_xor(dA, msk);
      dB += __shfl_xor(dB, msk);
    }
    float pA = __expf(dA), pB = __expf(dB);
    l += pA + pB;
    f32x2 vA0 = fp8dec<true>(uA.x), vA1 = fp8dec<true>(uA.y),
          vA2 = fp8dec<true>(uA.z), vA3 = fp8dec<true>(uA.w);
    f32x2 vB0 = fp8dec<true>(uB.x), vB1 = fp8dec<true>(uB.y),
          vB2 = fp8dec<true>(uB.z), vB3 = fp8dec<true>(uB.w);
    a0 += pA * vA0.x + pB * vB0.x;
    a1 += pA * vA0.y + pB * vB0.y;
    a2 += pA * vA1.x + pB * vB1.x;
    a3 += pA * vA1.y + pB * vB1.y;
    a4 += pA * vA2.x + pB * vB2.x;
    a5 += pA * vA2.y + pB * vB2.y;
    a6 += pA * vA3.x + pB * vB3.x;
    a7 += pA * vA3.y + pB * vB3.y;
  }
  for (; j < r1; j += 4) {           // masked tail: 4 groups x 1 edge per pass
    int e = j + g;
    bool v = e < r1;
    int s = esrc[v ? e : r0];
    uint4 u = *(const uint4*)(kvb + s);
    f32x2 k0 = fp8dec<false>(u.x), k1 = fp8dec<false>(u.y),
          k2 = fp8dec<false>(u.z), k3 = fp8dec<false>(u.w);
    float d = q0 * k0.x + q1 * k0.y + q2 * k1.x + q3 * k1.y
            + q4 * k2.x + q5 * k2.y + q6 * k3.x + q7 * k3.y;
#pragma unroll
    for (int msk = 1; msk <= 2; msk <<= 1) d += __shfl_xor(d, msk);
    float p = v ? __expf(d) : 0.f;
    l += p;
    f32x2 v0 = fp8dec<true>(u.x), v1 = fp8dec<true>(u.y),
          v2 = fp8dec<true>(u.z), v3 = fp8dec<true>(u.w);
    a0 += p * v0.x; a1 += p * v0.y; a2 += p * v1.x; a3 += p * v1.y;
    a4 += p * v2.x; a5 += p * v2.y; a6 += p * v3.x; a7 += p * v3.y;
  }
  // cross-group combine (same ll across 4 groups)
#pragma unroll
  for (int msk = 16; msk <= 32; msk <<= 1) {
    l  += __shfl_xor(l, msk);
    a0 += __shfl_xor(a0, msk);
    a1 += __shfl_xor(a1, msk);
    a2 += __shfl_xor(a2, msk);
    a3 += __shfl_xor(a3, msk);
    a4 += __shfl_xor(a4, msk);
    a5 += __shfl_xor(a5, msk);
    a6 += __shfl_xor(a6, msk);
    a7 += __shfl_xor(a7, msk);
  }
  float inv = (l > 0.f) ? 1.f / l : 0.f;
  if (g == 0) {
    uint4 sk = *(const uint4*)(SK + (size_t)node * 128 + ll * 8);
    float o0 = fmaxf(bflo(sk.x) + a0 * inv, 0.f);
    float o1 = fmaxf(bfhi(sk.x) + a1 * inv, 0.f);
    float o2 = fmaxf(bflo(sk.y) + a2 * inv, 0.f);
    float o3 = fmaxf(bfhi(sk.y) + a3 * inv, 0.f);
    float o4 = fmaxf(bflo(sk.z) + a4 * inv, 0.f);
    float o5 = fmaxf(bfhi(sk.z) + a5 * inv, 0.f);
    float o6 = fmaxf(bflo(sk.w) + a6 * inv, 0.f);
    float o7 = fmaxf(bfhi(sk.w) + a7 * inv, 0.f);
    uint4 hb;
    hb.x = ((unsigned)f2bf(o1) << 16) | (unsigned)f2bf(o0);
    hb.y = ((unsigned)f2bf(o3) << 16) | (unsigned)f2bf(o2);
    hb.z = ((unsigned)f2bf(o5) << 16) | (unsigned)f2bf(o4);
    hb.w = ((unsigned)f2bf(o7) << 16) | (unsigned)f2bf(o6);
    *(uint4*)(Hb + (size_t)node * 128 + ll * 8) = hb;
  }
}

// conv2 + fused relu/mean/Wo-dot: 8 lanes per edge (8 groups), uint2 (8 B/lane).
__global__ void node_attn2(const int* __restrict__ rowptr, const int* __restrict__ esrc,
                           const unsigned char* __restrict__ C2b, const float* __restrict__ Wo,
                           float* __restrict__ pblock, int n) {
  __shared__ float ps[4];
  int node = (blockIdx.x * blockDim.x + threadIdx.x) >> 6;
  int lane = threadIdx.x & 63;
  int wave = threadIdx.x >> 6;
  const int g = lane >> 3, gl = lane & 7;   // 8 groups x 8 lanes
  float t = 0.f;
  if (node < n) {
    const int r0 = rowptr[node], r1 = rowptr[node + 1];
    uint2 qu = *(const uint2*)(C2b + (size_t)node * 256 + gl * 8);
    const float q0 = bflo(qu.x), q1 = bfhi(qu.x), q2 = bflo(qu.y), q3 = bfhi(qu.y);
    float l = 0.f, a0 = 0.f, a1 = 0.f, a2 = 0.f, a3 = 0.f;
    const unsigned char* kvb = C2b + 64 + gl * 8;
    int j = r0;
    for (; j + 8 <= r1; j += 8) {    // 8 edges/wave-iter: 8 groups x 1 edge
      int s = esrc[j + g];
      uint2 u = *(const uint2*)(kvb + s);
      f32x2 k0 = fp8dec<false>(u.x), k1 = fp8dec<false>(u.y);
      float d = q0 * k0.x + q1 * k0.y + q2 * k1.x + q3 * k1.y;
#pragma unroll
      for (int msk = 1; msk <= 4; msk <<= 1) d += __shfl_xor(d, msk);
      float p = __expf(d);
      l += p;
      f32x2 v0 = fp8dec<true>(u.x), v1 = fp8dec<true>(u.y);
      a0 += p * v0.x; a1 += p * v0.y; a2 += p * v1.x; a3 += p * v1.y;
    }
    for (; j < r1; j += 8) {         // masked tail
      bool v = (j + g) < r1;
      int s = esrc[v ? j + g : r0];
      uint2 u = *(const uint2*)(kvb + s);
      f32x2 kd0 = fp8dec<false>(u.x), kd1 = fp8dec<false>(u.y);
      float d = q0 * kd0.x + q1 * kd0.y + q2 * kd1.x + q3 * kd1.y;
#pragma unroll
      for (int msk = 1; msk <= 4; msk <<= 1) d += __shfl_xor(d, msk);
      float p = v ? __expf(d) : 0.f;
      l += p;
      f32x2 vd0 = fp8dec<true>(u.x), vd1 = fp8dec<true>(u.y);
      a0 += p * vd0.x; a1 += p * vd0.y; a2 += p * vd1.x; a3 += p * vd1.y;
    }
    // cross-group combine (same gl across 8 groups)
#pragma unroll
    for (int msk = 8; msk <= 32; msk <<= 1) {
      l  += __shfl_xor(l, msk);
      a0 += __shfl_xor(a0, msk);
      a1 += __shfl_xor(a1, msk);
      a2 += __shfl_xor(a2, msk);
      a3 += __shfl_xor(a3, msk);
    }
    float inv = (l > 0.f) ? 1.f / l : 0.f;
    uint2 hu = *(const uint2*)(C2b + (size_t)node * 256 + 192 + gl * 8);
    float o0 = fmaxf(bflo(hu.x) + a0 * inv, 0.f);
    float o1 = fmaxf(bfhi(hu.x) + a1 * inv, 0.f);
    float o2 = fmaxf(bflo(hu.y) + a2 * inv, 0.f);
    float o3 = fmaxf(bfhi(hu.y) + a3 * inv, 0.f);
    t = o0 * Wo[4 * gl] + o1 * Wo[4 * gl + 1] + o2 * Wo[4 * gl + 2] + o3 * Wo[4 * gl + 3];
    // reduce over 8 gl-lanes
#pragma unroll
    for (int msk = 1; msk <= 4; msk <<= 1) t += __shfl_xor(t, msk);
  }
  if (lane == 0) ps[wave] = t;
  __syncthreads();
  if (threadIdx.x == 0) pblock[blockIdx.x] = ps[0] + ps[1] + ps[2] + ps[3];
}

// ---------------- final: sum per-block partials, scale, bias ----------------
// (kept as a kernel: single-address cross-XCD atomics for 12500 blocks risk
//  serialization -- G12 -- for a ~2 us saving)
__global__ void final_out(const float* __restrict__ pblock, const float* __restrict__ bo,
                          float* __restrict__ out, int nb, float invN) {
  __shared__ float s[256];
  float acc = 0.f;
  for (int i = threadIdx.x; i < nb; i += 256) acc += pblock[i];
  s[threadIdx.x] = acc;
  __syncthreads();
  for (int off = 128; off >= 1; off >>= 1) {
    if (threadIdx.x < off) s[threadIdx.x] += s[threadIdx.x + off];
    __syncthreads();
  }
  if (threadIdx.x == 0) out[0] = s[0] * invN + bo[0];
}

extern "C" void kernel_launch(void* const* d_in, const int* in_sizes, int n_in,
                              void* d_out, int out_size, void* d_ws, size_t ws_size,
                              hipStream_t stream) {
  const float* x   = (const float*)d_in[0];
  const int*   ei  = (const int*)d_in[1];  // [2, E]: row 0 = src, row 1 = dst
  const float* Wq1 = (const float*)d_in[2];  const float* bq1 = (const float*)d_in[3];
  const float* Wk1 = (const float*)d_in[4];  const float* bk1 = (const float*)d_in[5];
  const float* Wv1 = (const float*)d_in[6];  const float* bv1 = (const float*)d_in[7];
  const float* Ws1 = (const float*)d_in[8];  const float* bs1 = (const float*)d_in[9];
  const float* Wq2 = (const float*)d_in[10]; const float* bq2 = (const float*)d_in[11];
  const float* Wk2 = (const float*)d_in[12]; const float* bk2 = (const float*)d_in[13];
  const float* Wv2 = (const float*)d_in[14]; const float* bv2 = (const float*)d_in[15];
  const float* Ws2 = (const float*)d_in[16]; const float* bs2 = (const float*)d_in[17];
  const float* Wo  = (const float*)d_in[18]; const float* bo  = (const float*)d_in[19];

  char* ws = (char*)d_ws;
  const int N = N_NODES, E = N_EDGES;
  const int GB = (N + 63) / 64;
  const int EB = (E + 4095) / 4096;
  const int AB = (N * 64) / 256;   // 12500 attn blocks

  // buffers
  unsigned short* Q1b = (unsigned short*)(ws + 0);          // N*128 bf16 (pre-scaled)
  unsigned short* SK1 = (unsigned short*)(ws + 12800000);   // N*128 bf16
  unsigned char*  KV1 = (unsigned char*)(ws + 25600000);    // N*256 fp8
  unsigned short* H1b = (unsigned short*)(ws + 51200000);   // N*128 bf16
  unsigned char*  C2  = (unsigned char*)(ws + 64000000);    // N*256 bytes [Q|KV8|pad|H]
  // CSR + weights + misc
  int* rowptr = (int*)(ws + 89600000);                      // N+1
  int* esrc   = (int*)(ws + 89900032);                      // E (byte offsets, src<<8)
  int* bhist  = (int*)(ws + 93100032);                      // NBK (1 KB slot)
  int* bcur   = (int*)(ws + 93101056);                      // NBK (1 KB slot, adjacent)
  unsigned short* Wt1   = (unsigned short*)(ws + 93103104);   // 512x128 bf16
  unsigned short* Wt2   = (unsigned short*)(ws + 93234176);   // 128x128 bf16
  float*          bcat1 = (float*)(ws + 93266944);
  float*          bcat2 = (float*)(ws + 93268992);
  float*          pblock = (float*)(ws + 93269504);         // 12500 floats
  int*            ebuck = (int*)(ws + 93319552);            // E * 4B packed

  float* out = (float*)d_out;

  dim3 blk(256);

  // zero bhist + bcur in one contiguous memset (2 x 1 KB)
  hipMemsetAsync(bhist, 0, 2048, stream);

  // ---- L1: bucket histogram ----
  edge_hist<<<dim3(EB), blk, 0, stream>>>(ei, bhist, E);

  // ---- L2: bucket scatter (local bhist scan) + weight prep (independent) ----
  scatter_w<<<dim3(EB + W1_B + W2_B), blk, 0, stream>>>(
      ei, bhist, bcur, ebuck, E, EB,
      Wq1, Wk1, Wv1, Ws1, bq1, bk1, bv1, bs1,
      Wq2, Wk2, Wv2, Ws2, bq2, bk2, bv2, bs2,
      Wt1, bcat1, Wt2, bcat2);

  // ---- L3: bucket_csr (needs scatter) + conv1 GEMM (needs weights) ----
  csr_gemm1<<<dim3(NBK + GB), blk, 0, stream>>>(
      ebuck, bhist, rowptr, esrc, N, x, Wt1, bcat1, Q1b, SK1, KV1, N);

  // ---- conv1 fused attention + skip + relu -> bf16 ----
  node_attn1<<<dim3(AB), blk, 0, stream>>>(rowptr, esrc, Q1b, KV1, SK1, H1b, N);

  // ---- conv2 GEMM (fused Q|KV8|H rows) ----
  gemm2<<<dim3(GB), blk, 0, stream>>>(H1b, Wt2, bcat2, C2, N);

  // ---- conv2 attention + fused relu/mean/Wo-dot -> per-block partials ----
  node_attn2<<<dim3(AB), blk, 0, stream>>>(rowptr, esrc, C2, Wo, pblock, N);

  // ---- final reduce ----
  final_out<<<dim3(1), blk, 0, stream>>>(pblock, bo, out, AB, 1.0f / (float)N);
}

// Round 7
// 241.423 us; speedup vs baseline: 1.0146x; 1.0146x over previous
//
#include <hip/hip_runtime.h>
#include <math.h>

#define N_NODES 50000
#define N_EDGES 800000
#define NBK 196          // dst buckets of 256 nodes: bucket = dst >> 8
#define BCAP 6144        // max edges per bucket handled in LDS (mean 4082, sigma 64)

typedef short short8 __attribute__((ext_vector_type(8)));
typedef float f32x4 __attribute__((ext_vector_type(4)));
typedef float f32x2 __attribute__((ext_vector_type(2)));

// ---------------- bf16 / fp8 helpers ----------------
__device__ inline unsigned short f2bf(float v) {
  unsigned u = __float_as_uint(v);
  u += 0x7FFFu + ((u >> 16) & 1u);  // round-to-nearest-even
  return (unsigned short)(u >> 16);
}
__device__ inline float bf2f(unsigned short b) {
  return __uint_as_float(((unsigned)b) << 16);
}
__device__ inline float bflo(unsigned u) { return __uint_as_float(u << 16); }
__device__ inline float bfhi(unsigned u) { return __uint_as_float(u & 0xFFFF0000u); }
// fp8 e4m3 (OCP on gfx950); decode selector must be an immediate -> template param.
__device__ inline unsigned char f2fp8(float v) {
  return (unsigned char)(__builtin_amdgcn_cvt_pk_fp8_f32(v, 0.f, 0, false) & 0xFF);
}
template <bool HI>
__device__ inline f32x2 fp8dec(unsigned u) {
  return __builtin_amdgcn_cvt_pk_f32_fp8(u, HI);
}

#define SCL 0.17677669529663687f   // 1/sqrt(32), folded into Wq/bq at prep

// ---------------- fused prep: weight concat/transpose + bucket histogram ----------------
// (r6 lesson: a standalone histogram launch re-reads 3.2 MB serially; keeping it fused
//  here runs it concurrently with the weight transpose blocks for free.)
#define W1_B 256      // 512*128 / 256
#define W2_B 64       // 128*128 / 256
__global__ void prep_fused(const float* __restrict__ Wq1, const float* __restrict__ Wk1,
                           const float* __restrict__ Wv1, const float* __restrict__ Ws1,
                           const float* __restrict__ bq1, const float* __restrict__ bk1,
                           const float* __restrict__ bv1, const float* __restrict__ bs1,
                           const float* __restrict__ Wq2, const float* __restrict__ Wk2,
                           const float* __restrict__ Wv2, const float* __restrict__ Ws2,
                           const float* __restrict__ bq2, const float* __restrict__ bk2,
                           const float* __restrict__ bv2, const float* __restrict__ bs2,
                           unsigned short* __restrict__ Wt1, float* __restrict__ bcat1,
                           unsigned short* __restrict__ Wt2, float* __restrict__ bcat2,
                           const int* __restrict__ ei, int* __restrict__ bhist, int E) {
  const int b = blockIdx.x, tid = threadIdx.x;
  if (b < W1_B) {
    int i = b * 256 + tid;   // over 512*128
    int c = i >> 7, k = i & 127;
    int mi = c >> 7, lc = c & 127;
    const float* W = (mi == 0) ? Wq1 : (mi == 1) ? Wk1 : (mi == 2) ? Wv1 : Ws1;
    float scl = (mi == 0) ? SCL : 1.f;
    Wt1[i] = f2bf(W[(size_t)k * 128 + lc] * scl);
    if (i < 512) {
      int bm = i >> 7, bl = i & 127;
      const float* bb = (bm == 0) ? bq1 : (bm == 1) ? bk1 : (bm == 2) ? bv1 : bs1;
      bcat1[i] = bb[bl] * ((bm == 0) ? SCL : 1.f);
    }
  } else if (b < W1_B + W2_B) {
    int i = (b - W1_B) * 256 + tid;  // over 128*128
    int c = i >> 7, k = i & 127;
    int mi = c >> 5, lc = c & 31;
    const float* W = (mi == 0) ? Wq2 : (mi == 1) ? Wk2 : (mi == 2) ? Wv2 : Ws2;
    float scl = (mi == 0) ? SCL : 1.f;
    Wt2[i] = f2bf(W[(size_t)k * 32 + lc] * scl);
    if (i < 128) {
      int bm = i >> 5, bl = i & 31;
      const float* bb = (bm == 0) ? bq2 : (bm == 1) ? bk2 : (bm == 2) ? bv2 : bs2;
      bcat2[i] = bb[bl] * ((bm == 0) ? SCL : 1.f);
    }
  } else {
    __shared__ int h[NBK];
    for (int i = tid; i < NBK; i += 256) h[i] = 0;
    __syncthreads();
    int e = (b - W1_B - W2_B) * 4096 + tid;
#pragma unroll
    for (int p = 0; p < 16; ++p, e += 256)
      if (e < E) atomicAdd(&h[ei[E + e] >> 8], 1);
    __syncthreads();
    for (int i = tid; i < NBK; i += 256)
      if (h[i]) atomicAdd(&bhist[i], h[i]);
  }
}

// ================= FUSED: bucket_scatter (blocks [0,EB)) + conv1 GEMM (blocks [EB,EB+GB)) ====
// Scatter: LDS-aggregated two-phase bucket scatter -> contiguous slot chunks per block
// (write-combining friendly; WRITE == logical 41.7 MB; verified r0/r1). The old 1-block
// bucket_scan kernel is DELETED: each scatter block computes the 196-int exclusive
// prefix of bhist locally (~1 us Hillis-Steele, hidden under the gemm blocks); chunk
// base = bl[i] + atomicAdd(&bcur[i], cnt) with bcur zero-initialized -- bit-identical
// slot assignment (this local-scan variant was correctness-proven in r6).
// GEMM: 64 rows x 512 cols in TWO 256-col passes (acc[4][4]) keeping natural VGPR well
// below the 168 hint (r2 lesson: binding caps -> catastrophic spill roulette).
// r4 lesson: do NOT barrier-fuse attention with GEMMs (max-over-waves imbalance).
// KV fp8 row (256 B/node): byte 4t+{0,1} = K[2t,2t+1], byte 4t+{2,3} = V[2t,2t+1].
// ebuck packed: (src<<8) | (dst & 255).
__global__ __launch_bounds__(256, 3) void scatter_gemm1(
    const int* __restrict__ ei, const int* __restrict__ bhist, int* __restrict__ bcur,
    int* __restrict__ ebuck, int E, int EB,
    const float* __restrict__ X, const unsigned short* __restrict__ Wt,
    const float* __restrict__ bcat, unsigned short* __restrict__ Q1b,
    unsigned short* __restrict__ SK1, unsigned char* __restrict__ KV8, int M) {
  __shared__ __align__(16) unsigned char L[3][64 * 272];  // 52.2 KB
  const int tid = threadIdx.x;

  if ((int)blockIdx.x < EB) {
    // ---------- scatter path (uses first 3 KB of L as ints) ----------
    int* sc = (int*)L[0];          // 256 ints: inclusive scan
    int* bl = sc + 256;            // 256 ints: exclusive prefix (== old boff)
    int* lh = bl + 256;            // 256 ints: local histogram / chunk cursor
    const int t = tid;
    int v = (t < NBK) ? bhist[t] : 0;
    sc[t] = v;
    __syncthreads();
#pragma unroll
    for (int off = 1; off < 256; off <<= 1) {
      int u = (t >= off) ? sc[t - off] : 0;
      __syncthreads();
      sc[t] += u;
      __syncthreads();
    }
    bl[t] = sc[t] - v;
    lh[t] = 0;
    __syncthreads();
    const int e0 = blockIdx.x * 4096;
    int pks[16], bks[16];
#pragma unroll
    for (int p = 0; p < 16; ++p) {
      int e = e0 + p * 256 + tid;
      if (e < E) {
        int src = ei[e], dst = ei[E + e];
        pks[p] = (src << 8) | (dst & 255);
        bks[p] = dst >> 8;
        atomicAdd(&lh[bks[p]], 1);
      } else bks[p] = -1;
    }
    __syncthreads();
    for (int i = tid; i < NBK; i += 256)
      if (lh[i]) lh[i] = bl[i] + atomicAdd(&bcur[i], lh[i]);
    __syncthreads();
#pragma unroll
    for (int p = 0; p < 16; ++p) {
      if (bks[p] >= 0) {
        int slot = atomicAdd(&lh[bks[p]], 1);
        ebuck[slot] = pks[p];
      }
    }
    return;
  }

  // ---------- GEMM path (two passes, low register pressure) ----------
  unsigned short* As = (unsigned short*)L[0];             // stride 136 shorts
  const int bm = (blockIdx.x - EB) * 64;
  const int wave = tid >> 6, lane = tid & 63;
  const int lr = lane & 15, q = lane >> 4;

#pragma unroll
  for (int p = 0; p < 8; ++p) {
    int f = tid + p * 256;          // 0..2047 float4s
    int row = f >> 5, c4 = f & 31;
    int gm = bm + row; if (gm >= M) gm = 0;
    float4 v = *(const float4*)(X + (size_t)gm * 128 + c4 * 4);
    ushort4 o;
    o.x = f2bf(v.x); o.y = f2bf(v.y); o.z = f2bf(v.z); o.w = f2bf(v.w);
    *(ushort4*)&As[row * 136 + c4 * 4] = o;
  }
  __syncthreads();

#pragma unroll
  for (int pass = 0; pass < 2; ++pass) {
    const int colbase = pass * 256 + wave * 64;
    f32x4 acc[4][4];
#pragma unroll
    for (int i = 0; i < 4; ++i)
#pragma unroll
      for (int j = 0; j < 4; ++j) acc[i][j] = (f32x4){0.f, 0.f, 0.f, 0.f};

#pragma unroll
    for (int ks = 0; ks < 4; ++ks) {
      short8 af[4];
#pragma unroll
      for (int i = 0; i < 4; ++i)
        af[i] = *(short8*)&As[(i * 16 + lr) * 136 + ks * 32 + q * 8];
#pragma unroll
      for (int j = 0; j < 4; ++j) {
        short8 bf = *(const short8*)(Wt + (size_t)(colbase + j * 16 + lr) * 128 + ks * 32 + q * 8);
#pragma unroll
        for (int i = 0; i < 4; ++i)
          acc[i][j] = __builtin_amdgcn_mfma_f32_16x16x32_bf16(af[i], bf, acc[i][j], 0, 0, 0);
      }
    }

    float bj[4];
#pragma unroll
    for (int j = 0; j < 4; ++j) bj[j] = bcat[colbase + j * 16 + lr];

    if (pass == 0) {
      if (wave < 2) {          // Q cols 0..127 -> L[1] bf16
        unsigned short* Ls16 = (unsigned short*)L[1];
#pragma unroll
        for (int i = 0; i < 4; ++i)
#pragma unroll
          for (int r = 0; r < 4; ++r) {
            int row = i * 16 + q * 4 + r;
#pragma unroll
            for (int j = 0; j < 4; ++j)
              Ls16[row * 136 + wave * 64 + j * 16 + lr] = f2bf(acc[i][j][r] + bj[j]);
          }
      } else {                 // K dims 0..127 -> L[2] fp8 (voff 0)
        unsigned char* KLs = L[2];
#pragma unroll
        for (int i = 0; i < 4; ++i)
#pragma unroll
          for (int r = 0; r < 4; ++r) {
            int row = i * 16 + q * 4 + r;
#pragma unroll
            for (int j = 0; j < 4; ++j) {
              int d = (wave - 2) * 64 + j * 16 + lr;
              KLs[row * 272 + 4 * (d >> 1) + (d & 1)] = f2fp8(acc[i][j][r] + bj[j]);
            }
          }
      }
    } else {
      __syncthreads();         // all As (L[0]) reads complete before SK overwrites it
      if (wave < 2) {          // V dims 0..127 -> L[2] fp8 (voff 2)
        unsigned char* KLs = L[2];
#pragma unroll
        for (int i = 0; i < 4; ++i)
#pragma unroll
          for (int r = 0; r < 4; ++r) {
            int row = i * 16 + q * 4 + r;
#pragma unroll
            for (int j = 0; j < 4; ++j) {
              int d = wave * 64 + j * 16 + lr;
              KLs[row * 272 + 4 * (d >> 1) + 2 + (d & 1)] = f2fp8(acc[i][j][r] + bj[j]);
            }
          }
      } else {                 // SK cols 0..127 -> L[0] bf16 (As no longer needed)
        unsigned short* Ls16 = (unsigned short*)L[0];
#pragma unroll
        for (int i = 0; i < 4; ++i)
#pragma unroll
          for (int r = 0; r < 4; ++r) {
            int row = i * 16 + q * 4 + r;
#pragma unroll
            for (int j = 0; j < 4; ++j)
              Ls16[row * 136 + (wave - 2) * 64 + j * 16 + lr] = f2bf(acc[i][j][r] + bj[j]);
          }
      }
    }
  }
  __syncthreads();

#pragma unroll
  for (int p = 0; p < 4; ++p) {
    int f = tid + p * 256;
    int row = f >> 4, u = f & 15;
    int gr = bm + row;
    if (gr < M) {
      *(uint4*)(Q1b + (size_t)gr * 128 + u * 8) = *(uint4*)&((unsigned short*)L[1])[row * 136 + u * 8];
      *(uint4*)(KV8 + (size_t)gr * 256 + u * 16) = *(uint4*)&L[2][row * 272 + u * 16];
      *(uint4*)(SK1 + (size_t)gr * 128 + u * 8) = *(uint4*)&((unsigned short*)L[0])[row * 136 + u * 8];
    }
  }
}

// esrc stores src<<8 (byte offset into the 256B/node tables)
// lo/hi computed from a local bhist prefix scan (bucket_scan kernel deleted; r6-proven).
__global__ void bucket_csr(const int* __restrict__ ebuck, const int* __restrict__ bhist,
                           int* __restrict__ rowptr, int* __restrict__ esrc, int N) {
  const int b = blockIdx.x;
  __shared__ int s_scan[256];
  __shared__ int hv[256];
  __shared__ int hist[256];
  __shared__ int cur[256];
  __shared__ int sorted[BCAP];
  const int t = threadIdx.x;
  int v0 = (t < NBK) ? bhist[t] : 0;
  hv[t] = v0;
  s_scan[t] = v0;
  __syncthreads();
#pragma unroll
  for (int off = 1; off < 256; off <<= 1) {
    int u = (t >= off) ? s_scan[t - off] : 0;
    __syncthreads();
    s_scan[t] += u;
    __syncthreads();
  }
  const int lo = s_scan[b] - hv[b], hi = s_scan[b];
  const int cnt = hi - lo;
  hist[t] = 0;
  __syncthreads();
  for (int i = t; i < cnt; i += 256) atomicAdd(&hist[ebuck[lo + i] & 255], 1);
  __syncthreads();
  int v = hist[t];
  sorted[t] = v;
  __syncthreads();
#pragma unroll
  for (int off = 1; off < 256; off <<= 1) {
    int u = (t >= off) ? sorted[t - off] : 0;
    __syncthreads();
    sorted[t] += u;
    __syncthreads();
  }
  int excl = sorted[t] - v;
  cur[t] = excl;
  int node = b * 256 + t;
  if (node <= N) rowptr[node] = lo + excl;
  __syncthreads();
  for (int i = t; i < cnt; i += 256) {
    int pk = ebuck[lo + i];
    int slot = atomicAdd(&cur[pk & 255], 1);
    if (slot < BCAP) sorted[slot] = pk;
    else esrc[lo + slot] = pk & 0xFFFFFF00;
  }
  __syncthreads();
  int lim = cnt < BCAP ? cnt : BCAP;
  for (int i = t; i < lim; i += 256) esrc[lo + i] = sorted[i] & 0xFFFFFF00;
}

// ---- gemm2: LDS-staged A (bf16); 128 cols -> C2 rows (256 B): [Q bf16 | KV fp8 | pad | H bf16] ----
__global__ __launch_bounds__(256) void gemm2(
    const unsigned short* __restrict__ Ab, const unsigned short* __restrict__ Wt,
    const float* __restrict__ bcat, unsigned char* __restrict__ C2b, int M) {
  __shared__ __align__(16) unsigned short As[64 * 136];
  __shared__ __align__(16) unsigned char Lsb[64 * 272];
  const int bm = blockIdx.x * 64;
  const int tid = threadIdx.x, wave = tid >> 6, lane = tid & 63;
  const int lr = lane & 15, q = lane >> 4;

#pragma unroll
  for (int p = 0; p < 4; ++p) {
    int f = tid + p * 256;
    int row = f >> 4, chunk = f & 15;
    int gm = bm + row; if (gm >= M) gm = 0;
    uint4 v = *(const uint4*)(Ab + (size_t)gm * 128 + chunk * 8);
    *(uint4*)&As[row * 136 + chunk * 8] = v;
  }
  __syncthreads();

  f32x4 acc[4][2];
#pragma unroll
  for (int i = 0; i < 4; ++i)
#pragma unroll
    for (int j = 0; j < 2; ++j) acc[i][j] = (f32x4){0.f, 0.f, 0.f, 0.f};

#pragma unroll
  for (int ks = 0; ks < 4; ++ks) {
    short8 af[4];
#pragma unroll
    for (int i = 0; i < 4; ++i)
      af[i] = *(short8*)&As[(i * 16 + lr) * 136 + ks * 32 + q * 8];
#pragma unroll
    for (int j = 0; j < 2; ++j) {
      short8 bf = *(const short8*)(Wt + (size_t)(wave * 32 + j * 16 + lr) * 128 + ks * 32 + q * 8);
#pragma unroll
      for (int i = 0; i < 4; ++i)
        acc[i][j] = __builtin_amdgcn_mfma_f32_16x16x32_bf16(af[i], bf, acc[i][j], 0, 0, 0);
    }
  }

  float bj[2];
#pragma unroll
  for (int j = 0; j < 2; ++j) bj[j] = bcat[wave * 32 + j * 16 + lr];
#pragma unroll
  for (int i = 0; i < 4; ++i)
#pragma unroll
    for (int r = 0; r < 4; ++r) {
      int row = i * 16 + q * 4 + r;
#pragma unroll
      for (int j = 0; j < 2; ++j) {
        int c = wave * 32 + j * 16 + lr;
        float val = acc[i][j][r] + bj[j];
        if (c < 32) {
          *(unsigned short*)&Lsb[row * 272 + 2 * c] = f2bf(val);
        } else if (c < 64) {
          int d = c - 32;
          Lsb[row * 272 + 64 + 4 * (d >> 1) + (d & 1)] = f2fp8(val);
        } else if (c < 96) {
          int d = c - 64;
          Lsb[row * 272 + 64 + 4 * (d >> 1) + 2 + (d & 1)] = f2fp8(val);
        } else {
          *(unsigned short*)&Lsb[row * 272 + 192 + 2 * (c - 96)] = f2bf(val);
        }
      }
    }
  __syncthreads();
#pragma unroll
  for (int p = 0; p < 16; ++p) {
    int idx = tid + p * 256;
    int row = idx >> 6, u = idx & 63;
    int gr = bm + row;
    if (gr < M) *(unsigned*)(C2b + (size_t)gr * 256 + u * 4) = *(const unsigned*)&Lsb[row * 272 + u * 4];
  }
}

// ================= fused aggregation: plain-exp softmax, fp8 K/V =================
// conv1: 16 lanes per edge (4 groups), uint4 (16 B/lane) KV loads; 2 edges in flight.
__global__ void node_attn1(const int* __restrict__ rowptr, const int* __restrict__ esrc,
                           const unsigned short* __restrict__ Qb,
                           const unsigned char* __restrict__ KV8,
                           const unsigned short* __restrict__ SK, unsigned short* __restrict__ Hb,
                           int n) {
  int node = (blockIdx.x * blockDim.x + threadIdx.x) >> 6;
  int lane = threadIdx.x & 63;
  if (node >= n) return;
  const int g = lane >> 4, ll = lane & 15;   // 4 groups x 16 lanes
  const int r0 = rowptr[node], r1 = rowptr[node + 1];
  uint4 qq = *(const uint4*)(Qb + (size_t)node * 128 + ll * 8);
  const float q0 = bflo(qq.x), q1 = bfhi(qq.x), q2 = bflo(qq.y), q3 = bfhi(qq.y);
  const float q4 = bflo(qq.z), q5 = bfhi(qq.z), q6 = bflo(qq.w), q7 = bfhi(qq.w);
  float l = 0.f;
  float a0 = 0.f, a1 = 0.f, a2 = 0.f, a3 = 0.f, a4 = 0.f, a5 = 0.f, a6 = 0.f, a7 = 0.f;
  const unsigned char* kvb = KV8 + ll * 16;
  int j = r0;
  for (; j + 8 <= r1; j += 8) {      // 8 edges/wave-iter: 4 groups x 2 edges
    int e = j + g * 2;
    int sA = esrc[e], sB = esrc[e + 1];
    uint4 uA = *(const uint4*)(kvb + sA);
    uint4 uB = *(const uint4*)(kvb + sB);
    f32x2 kA0 = fp8dec<false>(uA.x), kA1 = fp8dec<false>(uA.y),
          kA2 = fp8dec<false>(uA.z), kA3 = fp8dec<false>(uA.w);
    f32x2 kB0 = fp8dec<false>(uB.x), kB1 = fp8dec<false>(uB.y),
          kB2 = fp8dec<false>(uB.z), kB3 = fp8dec<false>(uB.w);
    float dA = q0 * kA0.x + q1 * kA0.y + q2 * kA1.x + q3 * kA1.y
             + q4 * kA2.x + q5 * kA2.y + q6 * kA3.x + q7 * kA3.y;
    float dB = q0 * kB0.x + q1 * kB0.y + q2 * kB1.x + q3 * kB1.y
             + q4 * kB2.x + q5 * kB2.y + q6 * kB3.x + q7 * kB3.y;
#pragma unroll
    for (int msk = 1; msk <= 2; msk <<= 1) {   // reduce within 4-lane heads
      dA += __shfl_xor(dA, msk);
      dB += __shfl_xor(dB, msk);
    }
    float pA = __expf(dA), pB = __expf(dB);
    l += pA + pB;
    f32x2 vA0 = fp8dec<true>(uA.x), vA1 = fp8dec<true>(uA.y),
          vA2 = fp8dec<true>(uA.z), vA3 = fp8dec<true>(uA.w);
    f32x2 vB0 = fp8dec<true>(uB.x), vB1 = fp8dec<true>(uB.y),
          vB2 = fp8dec<true>(uB.z), vB3 = fp8dec<true>(uB.w);
    a0 += pA * vA0.x + pB * vB0.x;
    a1 += pA * vA0.y + pB * vB0.y;
    a2 += pA * vA1.x + pB * vB1.x;
    a3 += pA * vA1.y + pB * vB1.y;
    a4 += pA * vA2.x + pB * vB2.x;
    a5 += pA * vA2.y + pB * vB2.y;
    a6 += pA * vA3.x + pB * vB3.x;
    a7 += pA * vA3.y + pB * vB3.y;
  }
  for (; j < r1; j += 4) {           // masked tail: 4 groups x 1 edge per pass
    int e = j + g;
    bool v = e < r1;
    int s = esrc[v ? e : r0];
    uint4 u = *(const uint4*)(kvb + s);
    f32x2 k0 = fp8dec<false>(u.x), k1 = fp8dec<false>(u.y),
          k2 = fp8dec<false>(u.z), k3 = fp8dec<false>(u.w);
    float d = q0 * k0.x + q1 * k0.y + q2 * k1.x + q3 * k1.y
            + q4 * k2.x + q5 * k2.y + q6 * k3.x + q7 * k3.y;
#pragma unroll
    for (int msk = 1; msk <= 2; msk <<= 1) d += __shfl_xor(d, msk);
    float p = v ? __expf(d) : 0.f;
    l += p;
    f32x2 v0 = fp8dec<true>(u.x), v1 = fp8dec<true>(u.y),
          v2 = fp8dec<true>(u.z), v3 = fp8dec<true>(u.w);
    a0 += p * v0.x; a1 += p * v0.y; a2 += p * v1.x; a3 += p * v1.y;
    a4 += p * v2.x; a5 += p * v2.y; a6 += p * v3.x; a7 += p * v3.y;
  }
  // cross-group combine (same ll across 4 groups)
#pragma unroll
  for (int msk = 16; msk <= 32; msk <<= 1) {
    l  += __shfl_xor(l, msk);
    a0 += __shfl_xor(a0, msk);
    a1 += __shfl_xor(a1, msk);
    a2 += __shfl_xor(a2, msk);
    a3 += __shfl_xor(a3, msk);
    a4 += __shfl_xor(a4, msk);
    a5 += __shfl_xor(a5, msk);
    a6 += __shfl_xor(a6, msk);
    a7 += __shfl_xor(a7, msk);
  }
  float inv = (l > 0.f) ? 1.f / l : 0.f;
  if (g == 0) {
    uint4 sk = *(const uint4*)(SK + (size_t)node * 128 + ll * 8);
    float o0 = fmaxf(bflo(sk.x) + a0 * inv, 0.f);
    float o1 = fmaxf(bfhi(sk.x) + a1 * inv, 0.f);
    float o2 = fmaxf(bflo(sk.y) + a2 * inv, 0.f);
    float o3 = fmaxf(bfhi(sk.y) + a3 * inv, 0.f);
    float o4 = fmaxf(bflo(sk.z) + a4 * inv, 0.f);
    float o5 = fmaxf(bfhi(sk.z) + a5 * inv, 0.f);
    float o6 = fmaxf(bflo(sk.w) + a6 * inv, 0.f);
    float o7 = fmaxf(bfhi(sk.w) + a7 * inv, 0.f);
    uint4 hb;
    hb.x = ((unsigned)f2bf(o1) << 16) | (unsigned)f2bf(o0);
    hb.y = ((unsigned)f2bf(o3) << 16) | (unsigned)f2bf(o2);
    hb.z = ((unsigned)f2bf(o5) << 16) | (unsigned)f2bf(o4);
    hb.w = ((unsigned)f2bf(o7) << 16) | (unsigned)f2bf(o6);
    *(uint4*)(Hb + (size_t)node * 128 + ll * 8) = hb;
  }
}

// conv2 + fused relu/mean/Wo-dot: 8 lanes per edge (8 groups), uint2 (8 B/lane).
__global__ void node_attn2(const int* __restrict__ rowptr, const int* __restrict__ esrc,
                           const unsigned char* __restrict__ C2b, const float* __restrict__ Wo,
                           float* __restrict__ pblock, int n) {
  __shared__ float ps[4];
  int node = (blockIdx.x * blockDim.x + threadIdx.x) >> 6;
  int lane = threadIdx.x & 63;
  int wave = threadIdx.x >> 6;
  const int g = lane >> 3, gl = lane & 7;   // 8 groups x 8 lanes
  float t = 0.f;
  if (node < n) {
    const int r0 = rowptr[node], r1 = rowptr[node + 1];
    uint2 qu = *(const uint2*)(C2b + (size_t)node * 256 + gl * 8);
    const float q0 = bflo(qu.x), q1 = bfhi(qu.x), q2 = bflo(qu.y), q3 = bfhi(qu.y);
    float l = 0.f, a0 = 0.f, a1 = 0.f, a2 = 0.f, a3 = 0.f;
    const unsigned char* kvb = C2b + 64 + gl * 8;
    int j = r0;
    for (; j + 8 <= r1; j += 8) {    // 8 edges/wave-iter: 8 groups x 1 edge
      int s = esrc[j + g];
      uint2 u = *(const uint2*)(kvb + s);
      f32x2 k0 = fp8dec<false>(u.x), k1 = fp8dec<false>(u.y);
      float d = q0 * k0.x + q1 * k0.y + q2 * k1.x + q3 * k1.y;
#pragma unroll
      for (int msk = 1; msk <= 4; msk <<= 1) d += __shfl_xor(d, msk);
      float p = __expf(d);
      l += p;
      f32x2 v0 = fp8dec<true>(u.x), v1 = fp8dec<true>(u.y);
      a0 += p * v0.x; a1 += p * v0.y; a2 += p * v1.x; a3 += p * v1.y;
    }
    for (; j < r1; j += 8) {         // masked tail
      bool v = (j + g) < r1;
      int s = esrc[v ? j + g : r0];
      uint2 u = *(const uint2*)(kvb + s);
      f32x2 kd0 = fp8dec<false>(u.x), kd1 = fp8dec<false>(u.y);
      float d = q0 * kd0.x + q1 * kd0.y + q2 * kd1.x + q3 * kd1.y;
#pragma unroll
      for (int msk = 1; msk <= 4; msk <<= 1) d += __shfl_xor(d, msk);
      float p = v ? __expf(d) : 0.f;
      l += p;
      f32x2 vd0 = fp8dec<true>(u.x), vd1 = fp8dec<true>(u.y);
      a0 += p * vd0.x; a1 += p * vd0.y; a2 += p * vd1.x; a3 += p * vd1.y;
    }
    // cross-group combine (same gl across 8 groups)
#pragma unroll
    for (int msk = 8; msk <= 32; msk <<= 1) {
      l  += __shfl_xor(l, msk);
      a0 += __shfl_xor(a0, msk);
      a1 += __shfl_xor(a1, msk);
      a2 += __shfl_xor(a2, msk);
      a3 += __shfl_xor(a3, msk);
    }
    float inv = (l > 0.f) ? 1.f / l : 0.f;
    uint2 hu = *(const uint2*)(C2b + (size_t)node * 256 + 192 + gl * 8);
    float o0 = fmaxf(bflo(hu.x) + a0 * inv, 0.f);
    float o1 = fmaxf(bfhi(hu.x) + a1 * inv, 0.f);
    float o2 = fmaxf(bflo(hu.y) + a2 * inv, 0.f);
    float o3 = fmaxf(bfhi(hu.y) + a3 * inv, 0.f);
    t = o0 * Wo[4 * gl] + o1 * Wo[4 * gl + 1] + o2 * Wo[4 * gl + 2] + o3 * Wo[4 * gl + 3];
    // reduce over 8 gl-lanes
#pragma unroll
    for (int msk = 1; msk <= 4; msk <<= 1) t += __shfl_xor(t, msk);
  }
  if (lane == 0) ps[wave] = t;
  __syncthreads();
  if (threadIdx.x == 0) pblock[blockIdx.x] = ps[0] + ps[1] + ps[2] + ps[3];
}

// ---------------- final: sum per-block partials, scale, bias ----------------
// (kept as a kernel: single-address cross-XCD atomics for 12500 blocks risk
//  serialization -- G12 -- for a ~2 us saving)
__global__ void final_out(const float* __restrict__ pblock, const float* __restrict__ bo,
                          float* __restrict__ out, int nb, float invN) {
  __shared__ float s[256];
  float acc = 0.f;
  for (int i = threadIdx.x; i < nb; i += 256) acc += pblock[i];
  s[threadIdx.x] = acc;
  __syncthreads();
  for (int off = 128; off >= 1; off >>= 1) {
    if (threadIdx.x < off) s[threadIdx.x] += s[threadIdx.x + off];
    __syncthreads();
  }
  if (threadIdx.x == 0) out[0] = s[0] * invN + bo[0];
}

extern "C" void kernel_launch(void* const* d_in, const int* in_sizes, int n_in,
                              void* d_out, int out_size, void* d_ws, size_t ws_size,
                              hipStream_t stream) {
  const float* x   = (const float*)d_in[0];
  const int*   ei  = (const int*)d_in[1];  // [2, E]: row 0 = src, row 1 = dst
  const float* Wq1 = (const float*)d_in[2];  const float* bq1 = (const float*)d_in[3];
  const float* Wk1 = (const float*)d_in[4];  const float* bk1 = (const float*)d_in[5];
  const float* Wv1 = (const float*)d_in[6];  const float* bv1 = (const float*)d_in[7];
  const float* Ws1 = (const float*)d_in[8];  const float* bs1 = (const float*)d_in[9];
  const float* Wq2 = (const float*)d_in[10]; const float* bq2 = (const float*)d_in[11];
  const float* Wk2 = (const float*)d_in[12]; const float* bk2 = (const float*)d_in[13];
  const float* Wv2 = (const float*)d_in[14]; const float* bv2 = (const float*)d_in[15];
  const float* Ws2 = (const float*)d_in[16]; const float* bs2 = (const float*)d_in[17];
  const float* Wo  = (const float*)d_in[18]; const float* bo  = (const float*)d_in[19];

  char* ws = (char*)d_ws;
  const int N = N_NODES, E = N_EDGES;
  const int GB = (N + 63) / 64;
  const int EB = (E + 4095) / 4096;
  const int AB = (N * 64) / 256;   // 12500 attn blocks

  // buffers
  unsigned short* Q1b = (unsigned short*)(ws + 0);          // N*128 bf16 (pre-scaled)
  unsigned short* SK1 = (unsigned short*)(ws + 12800000);   // N*128 bf16
  unsigned char*  KV1 = (unsigned char*)(ws + 25600000);    // N*256 fp8
  unsigned short* H1b = (unsigned short*)(ws + 51200000);   // N*128 bf16
  unsigned char*  C2  = (unsigned char*)(ws + 64000000);    // N*256 bytes [Q|KV8|pad|H]
  // CSR + weights + misc
  int* rowptr = (int*)(ws + 89600000);                      // N+1
  int* esrc   = (int*)(ws + 89900032);                      // E (byte offsets, src<<8)
  int* bhist  = (int*)(ws + 93100032);                      // NBK (1 KB slot)
  int* bcur   = (int*)(ws + 93101056);                      // NBK (1 KB slot, adjacent)
  unsigned short* Wt1   = (unsigned short*)(ws + 93103104);   // 512x128 bf16
  unsigned short* Wt2   = (unsigned short*)(ws + 93234176);   // 128x128 bf16
  float*          bcat1 = (float*)(ws + 93266944);
  float*          bcat2 = (float*)(ws + 93268992);
  float*          pblock = (float*)(ws + 93269504);         // 12500 floats
  int*            ebuck = (int*)(ws + 93319552);            // E * 4B packed

  float* out = (float*)d_out;

  dim3 blk(256);

  // zero bhist + bcur in one contiguous memset (2 x 1 KB)
  hipMemsetAsync(bhist, 0, 2048, stream);

  // ---- fused prep: weights + bucket histogram (concurrent) ----
  prep_fused<<<dim3(W1_B + W2_B + EB), blk, 0, stream>>>(
      Wq1, Wk1, Wv1, Ws1, bq1, bk1, bv1, bs1,
      Wq2, Wk2, Wv2, Ws2, bq2, bk2, bv2, bs2,
      Wt1, bcat1, Wt2, bcat2, ei, bhist, E);

  // ---- FUSED: edge scatter (local bhist scan) + conv1 GEMM (independent) ----
  scatter_gemm1<<<dim3(EB + GB), blk, 0, stream>>>(
      ei, bhist, bcur, ebuck, E, EB, x, Wt1, bcat1, Q1b, SK1, KV1, N);

  // ---- per-bucket CSR finalize (local bhist scan) ----
  bucket_csr<<<dim3(NBK), blk, 0, stream>>>(ebuck, bhist, rowptr, esrc, N);

  // ---- conv1 fused attention + skip + relu -> bf16 ----
  node_attn1<<<dim3(AB), blk, 0, stream>>>(rowptr, esrc, Q1b, KV1, SK1, H1b, N);

  // ---- conv2 GEMM (fused Q|KV8|H rows) ----
  gemm2<<<dim3(GB), blk, 0, stream>>>(H1b, Wt2, bcat2, C2, N);

  // ---- conv2 attention + fused relu/mean/Wo-dot -> per-block partials ----
  node_attn2<<<dim3(AB), blk, 0, stream>>>(rowptr, esrc, C2, Wo, pblock, N);

  // ---- final reduce ----
  final_out<<<dim3(1), blk, 0, stream>>>(pblock, bo, out, AB, 1.0f / (float)N);
}